// Round 12
// baseline (400.513 us; speedup 1.0000x reference)
//
#include <hip/hip_runtime.h>
#include <hip/hip_bf16.h>

#define N_NODES 50000
#define N_EDGES 800000
#define N_RELS 65
#define DIM 64
#define N_GRAPHS 512

// dst-chunk sort geometry
#define DCH 512                                   // nodes per dst-chunk
#define NCH 98                                    // ceil(50000/512)
#define SB3 256                                   // scatterc blocks
#define EC3 3125                                  // edges per scatterc block (256*3125 = 800000)

// (rel, src-window) key space for the final sort: gathers in msg walk a 1MB hb window
#define NSW 7                                     // src windows of 8192 nodes (50000/8192 -> 0..6)
#define NKEY (N_RELS * NSW)                       // 455

#define MSG_BLOCKS 2048
#define NWAVES (MSG_BLOCKS * 4)

typedef __attribute__((ext_vector_type(8))) short short8;
typedef __attribute__((ext_vector_type(4))) float f32x4;

// ================= K1 prep: h-convert + W transpose + per-block dst-chunk hist =================

__global__ __launch_bounds__(256) void prep_kernel(
    const float* __restrict__ x, const int* __restrict__ dst,
    __hip_bfloat16* __restrict__ y, int* __restrict__ blk_hist3,
    const float* __restrict__ W1, const float* __restrict__ W2,
    const float* __restrict__ W3,
    __hip_bfloat16* __restrict__ Wt1, __hip_bfloat16* __restrict__ Wt2,
    __hip_bfloat16* __restrict__ Wt3,
    int* __restrict__ done_flags) {
    __shared__ int chist[128];
    __shared__ float tile[64][65];
    int t = threadIdx.x, b = blockIdx.x;
    int gtid = b * 256 + t;

    if (gtid < 2) done_flags[gtid] = 0;

    // blocks 0..255: dst-chunk histogram of their 3125-edge slice
    if (b < SB3) {
        if (t < 128) chist[t] = 0;
        __syncthreads();
        int lo = b * EC3;
        #pragma unroll
        for (int k = 0; k < 13; ++k) {
            int i = lo + t + k * 256;
            if (i < lo + EC3) atomicAdd(&chist[dst[i] >> 9], 1);
        }
    }

    // grid-stride h conversion (f32 -> bf16, vectorized)
    for (int i = gtid; i < (N_NODES * DIM) / 4; i += 1024 * 256) {
        float4 v = *(const float4*)(x + (size_t)i * 4);
        unsigned short us[4];
        us[0] = __hip_bfloat16_raw(__float2bfloat16(v.x)).x;
        us[1] = __hip_bfloat16_raw(__float2bfloat16(v.y)).x;
        us[2] = __hip_bfloat16_raw(__float2bfloat16(v.z)).x;
        us[3] = __hip_bfloat16_raw(__float2bfloat16(v.w)).x;
        *(ushort4*)(y + (size_t)i * 4) = *(const ushort4*)us;
    }

    // W transpose+convert: blocks 256..450 (LDS-tiled, coalesced both sides)
    if (b >= SB3 && b < SB3 + 3 * N_RELS) {
        int bb = b - SB3;
        int which = bb / N_RELS, r = bb - which * N_RELS;
        const float* W = (which == 0) ? W1 : (which == 1) ? W2 : W3;
        __hip_bfloat16* Wt = (which == 0) ? Wt1 : (which == 1) ? Wt2 : Wt3;
        for (int i = t; i < 4096; i += 256) {
            int row = i >> 6, col = i & 63;
            tile[row][col] = W[(size_t)r * 4096 + i];
        }
        __syncthreads();
        for (int i = t; i < 4096; i += 256) {
            int row = i >> 6, col = i & 63;
            Wt[(size_t)r * 4096 + i] = __float2bfloat16(tile[col][row]);
        }
    }

    if (b < SB3) {
        __syncthreads();
        if (t < NCH) blk_hist3[t * SB3 + b] = chist[t];
    }
}

// ================= K2 chunkscan: per-chunk block offsets; last block: chunk_ptr + g_ptr =================

__global__ __launch_bounds__(256) void chunkscan_kernel(
    const int* __restrict__ blk_hist3, int* __restrict__ blk_off3,
    int* __restrict__ chunk_tot, int* __restrict__ chunk_ptr,
    const int* __restrict__ gid, int* __restrict__ g_ptr, int* __restrict__ cnt_g,
    int* __restrict__ done) {
    __shared__ int wsum[4];
    __shared__ int is_last;
    int r = blockIdx.x, t = threadIdx.x;
    int w = t >> 6, lane = t & 63;

    int v = blk_hist3[r * SB3 + t];
    int x = v;
    #pragma unroll
    for (int off = 1; off < 64; off <<= 1) {
        int y = __shfl_up(x, off);
        if (lane >= off) x += y;
    }
    if (lane == 63) wsum[w] = x;
    __syncthreads();
    int base = 0;
    for (int i = 0; i < w; ++i) base += wsum[i];
    blk_off3[r * SB3 + t] = base + x - v;

    if (t == 255) {
        __hip_atomic_store(&chunk_tot[r], base + x, __ATOMIC_RELAXED,
                           __HIP_MEMORY_SCOPE_AGENT);
        __threadfence();
        int ticket = atomicAdd(done, 1);
        is_last = (ticket == NCH - 1) ? 1 : 0;
    }
    __syncthreads();

    if (is_last) {
        if (t == 0) {
            int run = 0;
            for (int q = 0; q < NCH; ++q) {
                int vv = __hip_atomic_load(&chunk_tot[q], __ATOMIC_RELAXED,
                                           __HIP_MEMORY_SCOPE_AGENT);
                chunk_ptr[q] = run; run += vv;
            }
            chunk_ptr[NCH] = run;   // == N_EDGES
        }
        // graph segments via binary search (graph_ids sorted)
        for (int g = t; g < N_GRAPHS; g += 256) {
            int lo2 = 0, hi2 = N_NODES;
            while (lo2 < hi2) { int m = (lo2 + hi2) >> 1; if (gid[m] < g) lo2 = m + 1; else hi2 = m; }
            int a2 = lo2;
            lo2 = 0; hi2 = N_NODES;
            int g1 = g + 1;
            while (lo2 < hi2) { int m = (lo2 + hi2) >> 1; if (gid[m] < g1) lo2 = m + 1; else hi2 = m; }
            g_ptr[g] = a2;
            cnt_g[g] = lo2 - a2;
        }
    }
}

// ================= K3 scatterc: LDS-staged counting sort by dst-chunk (no global atomics) =========
// rec: src(16) | dl(9)<<16 | rel(7)<<25

__global__ __launch_bounds__(256) void scatterc_kernel(
    const int* __restrict__ et, const int* __restrict__ src,
    const int* __restrict__ dst, const int* __restrict__ blk_hist3,
    const int* __restrict__ blk_off3, const int* __restrict__ chunk_ptr,
    unsigned* __restrict__ epk2) {
    __shared__ unsigned srec[EC3];
    __shared__ unsigned char sbin[EC3];
    __shared__ int loff[NCH], lcur[NCH], gbase[NCH];
    __shared__ int wsum[4];
    int t = threadIdx.x, b = blockIdx.x;
    int w = t >> 6, lane = t & 63;

    int v = (t < NCH) ? blk_hist3[t * SB3 + b] : 0;
    int x = v;
    #pragma unroll
    for (int off = 1; off < 64; off <<= 1) {
        int y = __shfl_up(x, off);
        if (lane >= off) x += y;
    }
    if (lane == 63) wsum[w] = x;
    __syncthreads();
    int base = 0;
    for (int i = 0; i < w; ++i) base += wsum[i];
    if (t < NCH) {
        int pref = base + x - v;
        loff[t] = pref;
        lcur[t] = pref;
        gbase[t] = chunk_ptr[t] + blk_off3[t * SB3 + b];
    }
    __syncthreads();

    int lo = b * EC3;
    #pragma unroll
    for (int k = 0; k < 13; ++k) {
        int i = lo + t + k * 256;
        if (i < lo + EC3) {
            int d = dst[i];
            int bin = d >> 9;
            unsigned rec = (unsigned)src[i] | ((unsigned)(d & 511) << 16) |
                           ((unsigned)et[i] << 25);
            int pl = atomicAdd(&lcur[bin], 1);
            srec[pl] = rec;
            sbin[pl] = (unsigned char)bin;
        }
    }
    __syncthreads();

    #pragma unroll
    for (int k = 0; k < 13; ++k) {
        int i = t + k * 256;
        if (i < EC3) {
            int bin = sbin[i];
            epk2[gbase[bin] + i - loff[bin]] = srec[i];
        }
    }
}

// ================= K4 chunksort: per-chunk 512-bin dl sort -> dst-sorted records +
//                   row_ptr/cnt_d + per-chunk (rel,srcwin) histograms =================
// efin2[pos] = src(16) | rel(7)<<16 ; pos is the edge's global dst-sorted index (= dpos)

__global__ __launch_bounds__(256) void chunksort_kernel(
    const unsigned* __restrict__ epk2, const int* __restrict__ chunk_ptr,
    unsigned* __restrict__ efin2, int* __restrict__ cnt_d,
    int* __restrict__ row_ptr, int* __restrict__ keyh_g) {
    __shared__ int h512[DCH], off512[DCH], cur512[DCH];
    __shared__ int keyh[NKEY];
    __shared__ int wsum[4];
    int c = blockIdx.x, t = threadIdx.x;
    int w = t >> 6, lane = t & 63;
    int e0 = chunk_ptr[c], e1 = chunk_ptr[c + 1];
    int n = e1 - e0;

    h512[2 * t] = 0; h512[2 * t + 1] = 0;
    for (int k = t; k < NKEY; k += 256) keyh[k] = 0;
    __syncthreads();

    for (int i = t; i < n; i += 256) {
        unsigned v = epk2[e0 + i];            // L2-cold once; re-reads below are L2-hot
        atomicAdd(&h512[(v >> 16) & 511], 1);
        int srcw = (v & 0xFFFFu) >> 13;       // src window 0..6
        atomicAdd(&keyh[(v >> 25) * NSW + srcw], 1);
    }
    __syncthreads();

    int v0 = h512[2 * t], v1 = h512[2 * t + 1];
    int s = v0 + v1;
    int x = s;
    #pragma unroll
    for (int off = 1; off < 64; off <<= 1) {
        int y = __shfl_up(x, off);
        if (lane >= off) x += y;
    }
    if (lane == 63) wsum[w] = x;
    __syncthreads();
    int base = 0;
    for (int i = 0; i < w; ++i) base += wsum[i];
    int run = base + x - s;
    off512[2 * t] = run;
    off512[2 * t + 1] = run + v0;
    cur512[2 * t] = run;
    cur512[2 * t + 1] = run + v0;
    __syncthreads();   // off512[j] below is read cross-thread (R10 fix)

    // CSR for agg falls out of the sort for free
    #pragma unroll
    for (int j = t; j < DCH; j += 256) {
        int d = c * DCH + j;
        if (d < N_NODES) { cnt_d[d] = h512[j]; row_ptr[d] = e0 + off512[j]; }
    }
    for (int k = t; k < NKEY; k += 256) keyh_g[k * NCH + c] = keyh[k];
    __syncthreads();

    for (int i = t; i < n; i += 256) {
        unsigned v = epk2[e0 + i];
        int dl = (v >> 16) & 511;
        int pos = atomicAdd(&cur512[dl], 1);
        // scattered u32 writes within a 32KB window: L2 absorbs
        efin2[e0 + pos] = (v & 0xFFFFu) | ((v >> 25) << 16);
    }
}

// ================= K5 keyscan: scan per-chunk (rel,srcwin) hists; last block: key_ptr +
//                   rel_ptr + tile_base =================

__global__ __launch_bounds__(128) void keyscan_kernel(
    const int* __restrict__ keyh_g, int* __restrict__ blk_off_key,
    int* __restrict__ key_tot, int* __restrict__ key_ptr,
    int* __restrict__ rel_ptr, int* __restrict__ tile_base,
    int* __restrict__ done) {
    __shared__ int wsum2[2];
    int k = blockIdx.x, t = threadIdx.x;      // k = 0..NKEY-1
    int w = t >> 6, lane = t & 63;
    int v = (t < NCH) ? keyh_g[k * NCH + t] : 0;
    int x = v;
    #pragma unroll
    for (int off = 1; off < 64; off <<= 1) {
        int y = __shfl_up(x, off);
        if (lane >= off) x += y;
    }
    if (lane == 63) wsum2[w] = x;
    __syncthreads();
    int base = (w == 1) ? wsum2[0] : 0;
    if (t < NCH) blk_off_key[k * NCH + t] = base + x - v;

    if (t == 127) {
        int tot = wsum2[0] + wsum2[1];
        __hip_atomic_store(&key_tot[k], tot, __ATOMIC_RELAXED, __HIP_MEMORY_SCOPE_AGENT);
        __threadfence();
        int ticket = atomicAdd(done, 1);
        if (ticket == NKEY - 1) {
            int ss = 0;
            for (int q = 0; q < NKEY; ++q) {
                int vv = __hip_atomic_load(&key_tot[q], __ATOMIC_RELAXED,
                                           __HIP_MEMORY_SCOPE_AGENT);
                key_ptr[q] = ss; ss += vv;
            }
            key_ptr[NKEY] = N_EDGES;
            int tt = 0;
            for (int r = 0; r < N_RELS; ++r) {
                rel_ptr[r] = key_ptr[r * NSW];
                int rt = key_ptr[(r + 1) * NSW] - key_ptr[r * NSW];
                tile_base[r] = tt; tt += (rt + 15) >> 4;
            }
            rel_ptr[N_RELS] = N_EDGES;
            tile_base[N_RELS] = tt;
        }
    }
}

// ================= K6 keyscatter: (rel,srcwin) sort -> final (src, dpos) records ============
// epk3[p] = src(16) | dpos<<32 ; within a rel segment edges are src-window-major, so
// msg's h[src] gathers walk 1MB hb windows (L2-resident) instead of random 6.4MB.

__global__ __launch_bounds__(256) void keyscatter_kernel(
    const unsigned* __restrict__ efin2, const int* __restrict__ chunk_ptr,
    const int* __restrict__ key_ptr, const int* __restrict__ blk_off_key,
    unsigned long long* __restrict__ epk3) {
    __shared__ int lcur[NKEY];
    int c = blockIdx.x, t = threadIdx.x;
    int e0 = chunk_ptr[c], n = chunk_ptr[c + 1] - e0;
    for (int k = t; k < NKEY; k += 256)
        lcur[k] = key_ptr[k] + blk_off_key[k * NCH + c];
    __syncthreads();
    for (int i = t; i < n; i += 256) {
        unsigned v = efin2[e0 + i];
        int rel = v >> 16;
        int srcv = v & 0xFFFFu;
        int k = rel * NSW + (srcv >> 13);
        int pos = atomicAdd(&lcur[k], 1);
        epk3[pos] = (unsigned long long)srcv |
                    ((unsigned long long)(unsigned)(e0 + i) << 32);
    }
}

// ================= phase 1: MFMA message kernel — zero-LDS, 4-col-interleaved B (R5-exact) =======

__device__ inline unsigned pack2bf(float x, float y) {
    unsigned short ux = __hip_bfloat16_raw(__float2bfloat16(x)).x;
    unsigned short uy = __hip_bfloat16_raw(__float2bfloat16(y)).x;
    return (unsigned)ux | ((unsigned)uy << 16);
}

__global__ __launch_bounds__(256) void msg_mfma_kernel(
    const __hip_bfloat16* __restrict__ hb, const __hip_bfloat16* __restrict__ Wt,
    const int* __restrict__ rel_ptr, const int* __restrict__ tile_base,
    const unsigned long long* __restrict__ epk3,
    __hip_bfloat16* __restrict__ msg) {
    int t = threadIdx.x;
    int w = t >> 6, lane = t & 63;
    int quad = lane >> 4, m16 = lane & 15;
    int wave = blockIdx.x * 4 + w;

    int ntiles = tile_base[N_RELS];
    int tpw = (ntiles + NWAVES - 1) / NWAVES;
    int T = wave * tpw;
    int T1 = T + tpw; if (T1 > ntiles) T1 = ntiles;
    if (T >= T1) return;

    int r = 0;
    while (T >= tile_base[r + 1]) ++r;

    while (T < T1) {
        int chunk_end = tile_base[r + 1]; if (chunk_end > T1) chunk_end = T1;
        int e_base = rel_ptr[r], t_base = tile_base[r];
        int seg_end = rel_ptr[r + 1];

        const __hip_bfloat16* Wr = Wt + (size_t)r * (DIM * DIM);
        short8 bf00 = *(const short8*)(Wr + (4 * m16)     * DIM + quad * 8);
        short8 bf01 = *(const short8*)(Wr + (4 * m16 + 1) * DIM + quad * 8);
        short8 bf02 = *(const short8*)(Wr + (4 * m16 + 2) * DIM + quad * 8);
        short8 bf03 = *(const short8*)(Wr + (4 * m16 + 3) * DIM + quad * 8);
        short8 bf10 = *(const short8*)(Wr + (4 * m16)     * DIM + 32 + quad * 8);
        short8 bf11 = *(const short8*)(Wr + (4 * m16 + 1) * DIM + 32 + quad * 8);
        short8 bf12 = *(const short8*)(Wr + (4 * m16 + 2) * DIM + 32 + quad * 8);
        short8 bf13 = *(const short8*)(Wr + (4 * m16 + 3) * DIM + 32 + quad * 8);

        // final (src, dpos) precomputed by the sort — single 8B load, no dependent lookups
        auto loadidx = [&](int TT, int& sv, int& dp) {
            int TC = TT < chunk_end ? TT : chunk_end - 1;
            int i = e_base + (TC - t_base) * 16 + lane;
            if (i >= N_EDGES) i = N_EDGES - 1;
            unsigned long long e = epk3[i];
            sv = (int)(e & 0xFFFFu);
            dp = (int)(e >> 32);
        };
        auto gatherA = [&](int sv, short8& x0, short8& x1) {
            int s = __shfl(sv, m16);
            const __hip_bfloat16* hp = hb + (size_t)s * DIM + quad * 8;
            x0 = *(const short8*)hp;
            x1 = *(const short8*)(hp + 32);
        };

        int sv0, dp0, sv1, dp1, sv2, dp2;
        short8 a0c, a1c, a0n, a1n;
        loadidx(T,     sv0, dp0);
        loadidx(T + 1, sv1, dp1);
        gatherA(sv0, a0c, a1c);

        for (; T < chunk_end; ++T) {
            loadidx(T + 2, sv2, dp2);
            gatherA(sv1, a0n, a1n);

            int e0 = e_base + (T - t_base) * 16;
            int rows = seg_end - e0; if (rows > 16) rows = 16;

            f32x4 c0 = {0.f, 0.f, 0.f, 0.f}, c1 = c0, c2 = c0, c3 = c0;
            c0 = __builtin_amdgcn_mfma_f32_16x16x32_bf16(a0c, bf00, c0, 0, 0, 0);
            c1 = __builtin_amdgcn_mfma_f32_16x16x32_bf16(a0c, bf01, c1, 0, 0, 0);
            c2 = __builtin_amdgcn_mfma_f32_16x16x32_bf16(a0c, bf02, c2, 0, 0, 0);
            c3 = __builtin_amdgcn_mfma_f32_16x16x32_bf16(a0c, bf03, c3, 0, 0, 0);
            c0 = __builtin_amdgcn_mfma_f32_16x16x32_bf16(a1c, bf10, c0, 0, 0, 0);
            c1 = __builtin_amdgcn_mfma_f32_16x16x32_bf16(a1c, bf11, c1, 0, 0, 0);
            c2 = __builtin_amdgcn_mfma_f32_16x16x32_bf16(a1c, bf12, c2, 0, 0, 0);
            c3 = __builtin_amdgcn_mfma_f32_16x16x32_bf16(a1c, bf13, c3, 0, 0, 0);

            int dpr[4];
            #pragma unroll
            for (int g = 0; g < 4; ++g) dpr[g] = __shfl(dp0, quad * 4 + g);

            #pragma unroll
            for (int g = 0; g < 4; ++g) {
                if (quad * 4 + g < rows) {
                    uint2 pk;
                    pk.x = pack2bf(c0[g], c1[g]);
                    pk.y = pack2bf(c2[g], c3[g]);
                    *(uint2*)(msg + (size_t)dpr[g] * DIM + 4 * m16) = pk;
                }
            }

            sv0 = sv1; dp0 = dp1; sv1 = sv2; dp1 = dp2;
            a0c = a0n; a1c = a1n;
        }
        ++r;
        while (T < T1 && T >= tile_base[r + 1]) ++r;
    }
}

// ================= phase 2: vectorized pull-aggregate + bias + ReLU (R5-exact) =================

__global__ __launch_bounds__(256) void agg_kernel(
    const __hip_bfloat16* __restrict__ msg, const int* __restrict__ row_ptr,
    const int* __restrict__ cnt_d, const float* __restrict__ b,
    __hip_bfloat16* __restrict__ hout) {
    int wave = blockIdx.x * 4 + (threadIdx.x >> 6);
    int lane = threadIdx.x & 63;
    if (wave >= N_NODES) return;
    int j0 = row_ptr[wave];
    int n  = cnt_d[wave];
    int rgrp = lane >> 3, dgrp = lane & 7;

    float a[8] = {0.f, 0.f, 0.f, 0.f, 0.f, 0.f, 0.f, 0.f};
    for (int jj = 0; jj < n; jj += 8) {
        int row = jj + rgrp;
        if (row < n) {
            uint4 d = *(const uint4*)(msg + (size_t)(j0 + row) * DIM + dgrp * 8);
            a[0] += __uint_as_float(d.x << 16);
            a[1] += __uint_as_float(d.x & 0xffff0000u);
            a[2] += __uint_as_float(d.y << 16);
            a[3] += __uint_as_float(d.y & 0xffff0000u);
            a[4] += __uint_as_float(d.z << 16);
            a[5] += __uint_as_float(d.z & 0xffff0000u);
            a[6] += __uint_as_float(d.w << 16);
            a[7] += __uint_as_float(d.w & 0xffff0000u);
        }
    }
    #pragma unroll
    for (int i = 0; i < 8; ++i) {
        a[i] += __shfl_xor(a[i], 8);
        a[i] += __shfl_xor(a[i], 16);
        a[i] += __shfl_xor(a[i], 32);
    }
    if (rgrp == 0) {
        unsigned short us[8];
        #pragma unroll
        for (int i = 0; i < 8; ++i) {
            float v = a[i] + b[dgrp * 8 + i];
            us[i] = __hip_bfloat16_raw(__float2bfloat16(v > 0.f ? v : 0.f)).x;
        }
        *(uint4*)(hout + (size_t)wave * DIM + dgrp * 8) = *(const uint4*)us;
    }
}

// ================= fused pool + FC x3 + prediction head =================

__global__ __launch_bounds__(256) void poolfc_kernel(
    const __hip_bfloat16* __restrict__ h, const int* __restrict__ g_ptr,
    const int* __restrict__ cnt_g,
    const float* __restrict__ W1, const float* __restrict__ b1,
    const float* __restrict__ W2, const float* __restrict__ b2,
    const float* __restrict__ W3, const float* __restrict__ b3,
    const float* __restrict__ pW, const float* __restrict__ pb,
    float* __restrict__ out) {
    int wave = blockIdx.x * 4 + (threadIdx.x >> 6);
    int lane = threadIdx.x & 63;
    if (wave >= N_GRAPHS) return;
    int j0 = g_ptr[wave];
    int n  = cnt_g[wave];
    int rgrp = lane >> 3, dgrp = lane & 7;

    float a[8] = {0.f, 0.f, 0.f, 0.f, 0.f, 0.f, 0.f, 0.f};
    for (int jj = 0; jj < n; jj += 8) {
        int row = jj + rgrp;
        if (row < n) {
            uint4 d = *(const uint4*)(h + (size_t)(j0 + row) * DIM + dgrp * 8);
            a[0] += __uint_as_float(d.x << 16);
            a[1] += __uint_as_float(d.x & 0xffff0000u);
            a[2] += __uint_as_float(d.y << 16);
            a[3] += __uint_as_float(d.y & 0xffff0000u);
            a[4] += __uint_as_float(d.z << 16);
            a[5] += __uint_as_float(d.z & 0xffff0000u);
            a[6] += __uint_as_float(d.w << 16);
            a[7] += __uint_as_float(d.w & 0xffff0000u);
        }
    }
    #pragma unroll
    for (int i = 0; i < 8; ++i) {
        a[i] += __shfl_xor(a[i], 8);
        a[i] += __shfl_xor(a[i], 16);
        a[i] += __shfl_xor(a[i], 32);
    }
    float v;
    {
        float acc = b1[lane];
        #pragma unroll
        for (int o = 0; o < 8; ++o)
            #pragma unroll
            for (int q = 0; q < 8; ++q)
                acc += __shfl(a[o], q) * W1[(q * 8 + o) * DIM + lane];
        v = acc > 0.f ? acc : 0.f;
    }
    {
        float acc = b2[lane];
        #pragma unroll
        for (int d = 0; d < DIM; ++d)
            acc += __shfl(v, d) * W2[d * DIM + lane];
        v = acc > 0.f ? acc : 0.f;
    }
    {
        float acc = b3[lane];
        #pragma unroll
        for (int d = 0; d < DIM; ++d)
            acc += __shfl(v, d) * W3[d * DIM + lane];
        v = acc > 0.f ? acc : 0.f;
    }
    float p0 = v * pW[lane * 2 + 0];
    float p1 = v * pW[lane * 2 + 1];
    #pragma unroll
    for (int off = 32; off > 0; off >>= 1) {
        p0 += __shfl_down(p0, off);
        p1 += __shfl_down(p1, off);
    }
    if (lane == 0) {
        out[wave * 2 + 0] = p0 + pb[0];
        out[wave * 2 + 1] = p1 + pb[1];
    }
}

// ================= launch =================

extern "C" void kernel_launch(void* const* d_in, const int* in_sizes, int n_in,
                              void* d_out, int out_size, void* d_ws, size_t ws_size,
                              hipStream_t stream) {
    const float* node_feats = (const float*)d_in[0];
    const int*   etypes     = (const int*)d_in[1];
    const int*   src        = (const int*)d_in[2];
    const int*   dst        = (const int*)d_in[3];
    const int*   graph_ids  = (const int*)d_in[4];
    const float* W1 = (const float*)d_in[5];
    const float* b1 = (const float*)d_in[6];
    const float* W2 = (const float*)d_in[7];
    const float* b2 = (const float*)d_in[8];
    const float* W3 = (const float*)d_in[9];
    const float* b3 = (const float*)d_in[10];
    const float* fcW1 = (const float*)d_in[11];
    const float* fcb1 = (const float*)d_in[12];
    const float* fcW2 = (const float*)d_in[13];
    const float* fcb2 = (const float*)d_in[14];
    const float* fcW3 = (const float*)d_in[15];
    const float* fcb3 = (const float*)d_in[16];
    const float* pW = (const float*)d_in[17];
    const float* pb = (const float*)d_in[18];
    float* out = (float*)d_out;

    // workspace carve-up (256B aligned)
    char* p = (char*)d_ws;
    auto alloc = [&](size_t bytes) -> void* {
        void* r = (void*)p;
        p += (bytes + 255) & ~(size_t)255;
        return r;
    };
    int* blk_hist3  = (int*)alloc((size_t)NCH * SB3 * sizeof(int));
    int* blk_off3   = (int*)alloc((size_t)NCH * SB3 * sizeof(int));
    int* chunk_tot  = (int*)alloc(NCH * sizeof(int));
    int* chunk_ptr  = (int*)alloc((NCH + 1) * sizeof(int));
    unsigned* epk2  = (unsigned*)alloc((size_t)N_EDGES * sizeof(unsigned));
    unsigned* efin2 = (unsigned*)alloc((size_t)N_EDGES * sizeof(unsigned));
    unsigned long long* epk3 = (unsigned long long*)alloc((size_t)N_EDGES * sizeof(unsigned long long));
    int* keyh_g     = (int*)alloc((size_t)NKEY * NCH * sizeof(int));
    int* blk_off_key= (int*)alloc((size_t)NKEY * NCH * sizeof(int));
    int* key_tot    = (int*)alloc(NKEY * sizeof(int));
    int* key_ptr    = (int*)alloc((NKEY + 1) * sizeof(int));
    int* rel_ptr    = (int*)alloc((N_RELS + 1) * sizeof(int));
    int* tile_base  = (int*)alloc((N_RELS + 1) * sizeof(int));
    int* cnt_d      = (int*)alloc((size_t)N_NODES * sizeof(int));
    int* row_ptr    = (int*)alloc((size_t)N_NODES * sizeof(int));
    int* cnt_g      = (int*)alloc(N_GRAPHS * sizeof(int));
    int* g_ptr      = (int*)alloc(N_GRAPHS * sizeof(int));
    int* done_flags = (int*)alloc(2 * sizeof(int));
    __hip_bfloat16* hb0 = (__hip_bfloat16*)alloc((size_t)N_NODES * DIM * sizeof(__hip_bfloat16));
    __hip_bfloat16* hb1 = (__hip_bfloat16*)alloc((size_t)N_NODES * DIM * sizeof(__hip_bfloat16));
    __hip_bfloat16* Wt1 = (__hip_bfloat16*)alloc((size_t)N_RELS * DIM * DIM * sizeof(__hip_bfloat16));
    __hip_bfloat16* Wt2 = (__hip_bfloat16*)alloc((size_t)N_RELS * DIM * DIM * sizeof(__hip_bfloat16));
    __hip_bfloat16* Wt3 = (__hip_bfloat16*)alloc((size_t)N_RELS * DIM * DIM * sizeof(__hip_bfloat16));
    __hip_bfloat16* msg = (__hip_bfloat16*)alloc((size_t)N_EDGES * DIM * sizeof(__hip_bfloat16));

    const int AGG_BLOCKS = (N_NODES + 3) / 4;            // 12500

    // ---- prep: atomic-free two-level sort, (rel,srcwin)-keyed (6 dispatches) ----
    prep_kernel<<<1024, 256, 0, stream>>>(node_feats, dst, hb0, blk_hist3,
                                          W1, W2, W3, Wt1, Wt2, Wt3, done_flags);
    chunkscan_kernel<<<NCH, 256, 0, stream>>>(blk_hist3, blk_off3, chunk_tot, chunk_ptr,
                                              graph_ids, g_ptr, cnt_g, &done_flags[0]);
    scatterc_kernel<<<SB3, 256, 0, stream>>>(etypes, src, dst, blk_hist3, blk_off3,
                                             chunk_ptr, epk2);
    chunksort_kernel<<<NCH, 256, 0, stream>>>(epk2, chunk_ptr, efin2, cnt_d,
                                              row_ptr, keyh_g);
    keyscan_kernel<<<NKEY, 128, 0, stream>>>(keyh_g, blk_off_key, key_tot, key_ptr,
                                             rel_ptr, tile_base, &done_flags[1]);
    keyscatter_kernel<<<NCH, 256, 0, stream>>>(efin2, chunk_ptr, key_ptr,
                                               blk_off_key, epk3);

    // ---- 3 RGCN layers ----
    msg_mfma_kernel<<<MSG_BLOCKS, 256, 0, stream>>>(hb0, Wt1, rel_ptr, tile_base,
                                                    epk3, msg);
    agg_kernel<<<AGG_BLOCKS, 256, 0, stream>>>(msg, row_ptr, cnt_d, b1, hb1);

    msg_mfma_kernel<<<MSG_BLOCKS, 256, 0, stream>>>(hb1, Wt2, rel_ptr, tile_base,
                                                    epk3, msg);
    agg_kernel<<<AGG_BLOCKS, 256, 0, stream>>>(msg, row_ptr, cnt_d, b2, hb0);

    msg_mfma_kernel<<<MSG_BLOCKS, 256, 0, stream>>>(hb0, Wt3, rel_ptr, tile_base,
                                                    epk3, msg);
    agg_kernel<<<AGG_BLOCKS, 256, 0, stream>>>(msg, row_ptr, cnt_d, b3, hb1);

    // ---- fused pool + FC head ----
    poolfc_kernel<<<(N_GRAPHS + 3) / 4, 256, 0, stream>>>(hb1, g_ptr, cnt_g,
                                                          fcW1, fcb1, fcW2, fcb2,
                                                          fcW3, fcb3, pW, pb, out);
}

// Round 13
// 373.598 us; speedup vs baseline: 1.0720x; 1.0720x over previous
//
#include <hip/hip_runtime.h>
#include <hip/hip_bf16.h>

#define N_NODES 50000
#define N_EDGES 800000
#define N_RELS 65
#define DIM 64
#define N_GRAPHS 512

// dst-chunk sort geometry
#define DCH 512                                   // nodes per dst-chunk
#define NCH 98                                    // ceil(50000/512)
#define SB3 256                                   // scatterc blocks
#define EC3 3125                                  // edges per scatterc block (256*3125 = 800000)

// (rel, src-window) key space for the final sort: gathers in msg walk a 1MB hb window
#define NSW 7                                     // src windows of 8192 nodes (50000/8192 -> 0..6)
#define NKEY (N_RELS * NSW)                       // 455

#define MSG_BLOCKS 2048
#define NWAVES (MSG_BLOCKS * 4)

typedef __attribute__((ext_vector_type(8))) short short8;
typedef __attribute__((ext_vector_type(4))) float f32x4;

// ================= K1 prep: h-convert + W transpose + per-block dst-chunk hist =================

__global__ __launch_bounds__(256) void prep_kernel(
    const float* __restrict__ x, const int* __restrict__ dst,
    __hip_bfloat16* __restrict__ y, int* __restrict__ blk_hist3,
    const float* __restrict__ W1, const float* __restrict__ W2,
    const float* __restrict__ W3,
    __hip_bfloat16* __restrict__ Wt1, __hip_bfloat16* __restrict__ Wt2,
    __hip_bfloat16* __restrict__ Wt3,
    int* __restrict__ done_flags) {
    __shared__ int chist[128];
    __shared__ float tile[64][65];
    int t = threadIdx.x, b = blockIdx.x;
    int gtid = b * 256 + t;

    if (gtid < 2) done_flags[gtid] = 0;

    // blocks 0..255: dst-chunk histogram of their 3125-edge slice
    if (b < SB3) {
        if (t < 128) chist[t] = 0;
        __syncthreads();
        int lo = b * EC3;
        #pragma unroll
        for (int k = 0; k < 13; ++k) {
            int i = lo + t + k * 256;
            if (i < lo + EC3) atomicAdd(&chist[dst[i] >> 9], 1);
        }
    }

    // grid-stride h conversion (f32 -> bf16, vectorized)
    for (int i = gtid; i < (N_NODES * DIM) / 4; i += 1024 * 256) {
        float4 v = *(const float4*)(x + (size_t)i * 4);
        unsigned short us[4];
        us[0] = __hip_bfloat16_raw(__float2bfloat16(v.x)).x;
        us[1] = __hip_bfloat16_raw(__float2bfloat16(v.y)).x;
        us[2] = __hip_bfloat16_raw(__float2bfloat16(v.z)).x;
        us[3] = __hip_bfloat16_raw(__float2bfloat16(v.w)).x;
        *(ushort4*)(y + (size_t)i * 4) = *(const ushort4*)us;
    }

    // W transpose+convert: blocks 256..450 (LDS-tiled, coalesced both sides)
    if (b >= SB3 && b < SB3 + 3 * N_RELS) {
        int bb = b - SB3;
        int which = bb / N_RELS, r = bb - which * N_RELS;
        const float* W = (which == 0) ? W1 : (which == 1) ? W2 : W3;
        __hip_bfloat16* Wt = (which == 0) ? Wt1 : (which == 1) ? Wt2 : Wt3;
        for (int i = t; i < 4096; i += 256) {
            int row = i >> 6, col = i & 63;
            tile[row][col] = W[(size_t)r * 4096 + i];
        }
        __syncthreads();
        for (int i = t; i < 4096; i += 256) {
            int row = i >> 6, col = i & 63;
            Wt[(size_t)r * 4096 + i] = __float2bfloat16(tile[col][row]);
        }
    }

    if (b < SB3) {
        __syncthreads();
        if (t < NCH) blk_hist3[t * SB3 + b] = chist[t];
    }
}

// ================= K2 chunkscan: per-chunk block offsets; last block: chunk_ptr + g_ptr =================

__global__ __launch_bounds__(256) void chunkscan_kernel(
    const int* __restrict__ blk_hist3, int* __restrict__ blk_off3,
    int* __restrict__ chunk_tot, int* __restrict__ chunk_ptr,
    const int* __restrict__ gid, int* __restrict__ g_ptr, int* __restrict__ cnt_g,
    int* __restrict__ done) {
    __shared__ int wsum[4];
    __shared__ int is_last;
    int r = blockIdx.x, t = threadIdx.x;
    int w = t >> 6, lane = t & 63;

    int v = blk_hist3[r * SB3 + t];
    int x = v;
    #pragma unroll
    for (int off = 1; off < 64; off <<= 1) {
        int y = __shfl_up(x, off);
        if (lane >= off) x += y;
    }
    if (lane == 63) wsum[w] = x;
    __syncthreads();
    int base = 0;
    for (int i = 0; i < w; ++i) base += wsum[i];
    blk_off3[r * SB3 + t] = base + x - v;

    if (t == 255) {
        __hip_atomic_store(&chunk_tot[r], base + x, __ATOMIC_RELAXED,
                           __HIP_MEMORY_SCOPE_AGENT);
        __threadfence();
        int ticket = atomicAdd(done, 1);
        is_last = (ticket == NCH - 1) ? 1 : 0;
    }
    __syncthreads();

    if (is_last) {
        if (t == 0) {
            int run = 0;
            for (int q = 0; q < NCH; ++q) {
                int vv = __hip_atomic_load(&chunk_tot[q], __ATOMIC_RELAXED,
                                           __HIP_MEMORY_SCOPE_AGENT);
                chunk_ptr[q] = run; run += vv;
            }
            chunk_ptr[NCH] = run;   // == N_EDGES
        }
        // graph segments via binary search (graph_ids sorted)
        for (int g = t; g < N_GRAPHS; g += 256) {
            int lo2 = 0, hi2 = N_NODES;
            while (lo2 < hi2) { int m = (lo2 + hi2) >> 1; if (gid[m] < g) lo2 = m + 1; else hi2 = m; }
            int a2 = lo2;
            lo2 = 0; hi2 = N_NODES;
            int g1 = g + 1;
            while (lo2 < hi2) { int m = (lo2 + hi2) >> 1; if (gid[m] < g1) lo2 = m + 1; else hi2 = m; }
            g_ptr[g] = a2;
            cnt_g[g] = lo2 - a2;
        }
    }
}

// ================= K3 scatterc: LDS-staged counting sort by dst-chunk (no global atomics) =========
// rec: src(16) | dl(9)<<16 | rel(7)<<25

__global__ __launch_bounds__(256) void scatterc_kernel(
    const int* __restrict__ et, const int* __restrict__ src,
    const int* __restrict__ dst, const int* __restrict__ blk_hist3,
    const int* __restrict__ blk_off3, const int* __restrict__ chunk_ptr,
    unsigned* __restrict__ epk2) {
    __shared__ unsigned srec[EC3];
    __shared__ unsigned char sbin[EC3];
    __shared__ int loff[NCH], lcur[NCH], gbase[NCH];
    __shared__ int wsum[4];
    int t = threadIdx.x, b = blockIdx.x;
    int w = t >> 6, lane = t & 63;

    int v = (t < NCH) ? blk_hist3[t * SB3 + b] : 0;
    int x = v;
    #pragma unroll
    for (int off = 1; off < 64; off <<= 1) {
        int y = __shfl_up(x, off);
        if (lane >= off) x += y;
    }
    if (lane == 63) wsum[w] = x;
    __syncthreads();
    int base = 0;
    for (int i = 0; i < w; ++i) base += wsum[i];
    if (t < NCH) {
        int pref = base + x - v;
        loff[t] = pref;
        lcur[t] = pref;
        gbase[t] = chunk_ptr[t] + blk_off3[t * SB3 + b];
    }
    __syncthreads();

    int lo = b * EC3;
    #pragma unroll
    for (int k = 0; k < 13; ++k) {
        int i = lo + t + k * 256;
        if (i < lo + EC3) {
            int d = dst[i];
            int bin = d >> 9;
            unsigned rec = (unsigned)src[i] | ((unsigned)(d & 511) << 16) |
                           ((unsigned)et[i] << 25);
            int pl = atomicAdd(&lcur[bin], 1);
            srec[pl] = rec;
            sbin[pl] = (unsigned char)bin;
        }
    }
    __syncthreads();

    #pragma unroll
    for (int k = 0; k < 13; ++k) {
        int i = t + k * 256;
        if (i < EC3) {
            int bin = sbin[i];
            epk2[gbase[bin] + i - loff[bin]] = srec[i];
        }
    }
}

// ================= K4 chunksort: per-chunk 512-bin dl sort -> dst-sorted records +
//                   row_ptr/cnt_d + per-chunk (rel,srcwin) histograms =================
// efin2[pos] = src(16) | rel(7)<<16 ; pos is the edge's global dst-sorted index (= dpos)

__global__ __launch_bounds__(256) void chunksort_kernel(
    const unsigned* __restrict__ epk2, const int* __restrict__ chunk_ptr,
    unsigned* __restrict__ efin2, int* __restrict__ cnt_d,
    int* __restrict__ row_ptr, int* __restrict__ keyh_g) {
    __shared__ int h512[DCH], off512[DCH], cur512[DCH];
    __shared__ int keyh[NKEY];
    __shared__ int wsum[4];
    int c = blockIdx.x, t = threadIdx.x;
    int w = t >> 6, lane = t & 63;
    int e0 = chunk_ptr[c], e1 = chunk_ptr[c + 1];
    int n = e1 - e0;

    h512[2 * t] = 0; h512[2 * t + 1] = 0;
    for (int k = t; k < NKEY; k += 256) keyh[k] = 0;
    __syncthreads();

    for (int i = t; i < n; i += 256) {
        unsigned v = epk2[e0 + i];            // L2-cold once; re-reads below are L2-hot
        atomicAdd(&h512[(v >> 16) & 511], 1);
        int srcw = (v & 0xFFFFu) >> 13;       // src window 0..6
        atomicAdd(&keyh[(v >> 25) * NSW + srcw], 1);
    }
    __syncthreads();

    int v0 = h512[2 * t], v1 = h512[2 * t + 1];
    int s = v0 + v1;
    int x = s;
    #pragma unroll
    for (int off = 1; off < 64; off <<= 1) {
        int y = __shfl_up(x, off);
        if (lane >= off) x += y;
    }
    if (lane == 63) wsum[w] = x;
    __syncthreads();
    int base = 0;
    for (int i = 0; i < w; ++i) base += wsum[i];
    int run = base + x - s;
    off512[2 * t] = run;
    off512[2 * t + 1] = run + v0;
    cur512[2 * t] = run;
    cur512[2 * t + 1] = run + v0;
    __syncthreads();   // off512[j] below is read cross-thread (R10 fix)

    // CSR for agg falls out of the sort for free
    #pragma unroll
    for (int j = t; j < DCH; j += 256) {
        int d = c * DCH + j;
        if (d < N_NODES) { cnt_d[d] = h512[j]; row_ptr[d] = e0 + off512[j]; }
    }
    for (int k = t; k < NKEY; k += 256) keyh_g[k * NCH + c] = keyh[k];
    __syncthreads();

    for (int i = t; i < n; i += 256) {
        unsigned v = epk2[e0 + i];
        int dl = (v >> 16) & 511;
        int pos = atomicAdd(&cur512[dl], 1);
        // scattered u32 writes within a 32KB window: L2 absorbs
        efin2[e0 + pos] = (v & 0xFFFFu) | ((v >> 25) << 16);
    }
}

// ================= K5 keyscan: scan per-chunk (rel,srcwin) hists; last block does a
//                   PARALLEL scan of key_tot (R12 fix: the serial 455-iteration
//                   agent-scope loop was 45us; parallel loads hide the latency) =====

__global__ __launch_bounds__(128) void keyscan_kernel(
    const int* __restrict__ keyh_g, int* __restrict__ blk_off_key,
    int* __restrict__ key_tot, int* __restrict__ key_ptr,
    int* __restrict__ rel_ptr, int* __restrict__ tile_base,
    int* __restrict__ done) {
    __shared__ int wsum2[2];
    __shared__ int is_last;
    __shared__ int kp[NKEY + 1];
    int k = blockIdx.x, t = threadIdx.x;      // k = 0..NKEY-1
    int w = t >> 6, lane = t & 63;
    int v = (t < NCH) ? keyh_g[k * NCH + t] : 0;
    int x = v;
    #pragma unroll
    for (int off = 1; off < 64; off <<= 1) {
        int y = __shfl_up(x, off);
        if (lane >= off) x += y;
    }
    if (lane == 63) wsum2[w] = x;
    __syncthreads();
    int base = (w == 1) ? wsum2[0] : 0;
    if (t < NCH) blk_off_key[k * NCH + t] = base + x - v;

    if (t == 127) {
        int tot = wsum2[0] + wsum2[1];
        __hip_atomic_store(&key_tot[k], tot, __ATOMIC_RELAXED, __HIP_MEMORY_SCOPE_AGENT);
        __threadfence();
        int ticket = atomicAdd(done, 1);
        is_last = (ticket == NKEY - 1) ? 1 : 0;
    }
    __syncthreads();

    if (is_last) {
        // parallel scan over NKEY totals: thread t owns 4 consecutive entries.
        // All 455 agent-scope loads issue concurrently (latency overlapped).
        int vals[4]; int s2 = 0;
        #pragma unroll
        for (int j = 0; j < 4; ++j) {
            int idx = t * 4 + j;
            vals[j] = (idx < NKEY)
                          ? __hip_atomic_load(&key_tot[idx], __ATOMIC_RELAXED,
                                              __HIP_MEMORY_SCOPE_AGENT)
                          : 0;
            s2 += vals[j];
        }
        int x2 = s2;
        #pragma unroll
        for (int off = 1; off < 64; off <<= 1) {
            int y = __shfl_up(x2, off);
            if (lane >= off) x2 += y;
        }
        if (lane == 63) wsum2[w] = x2;
        __syncthreads();
        int base2 = (w == 1) ? wsum2[0] : 0;
        int run = base2 + x2 - s2;
        #pragma unroll
        for (int j = 0; j < 4; ++j) {
            int idx = t * 4 + j;
            if (idx <= NKEY) kp[idx] = run;
            run += vals[j];
        }
        __syncthreads();
        for (int i = t; i <= NKEY; i += 128) key_ptr[i] = kp[i];
        if (t == 0) {
            kp[NKEY] = N_EDGES;
            int tt = 0;
            for (int r = 0; r < N_RELS; ++r) {      // 65 LDS iterations — cheap
                rel_ptr[r] = kp[r * NSW];
                int rt = kp[(r + 1) * NSW] - kp[r * NSW];
                tile_base[r] = tt; tt += (rt + 15) >> 4;
            }
            rel_ptr[N_RELS] = N_EDGES;
            tile_base[N_RELS] = tt;
        }
    }
}

// ================= K6 keyscatter: (rel,srcwin) sort -> final (src, dpos) records ============
// epk3[p] = src(16) | dpos<<32 ; within a rel segment edges are src-window-major, so
// msg's h[src] gathers walk 1MB hb windows (L2-resident) instead of random 6.4MB.

__global__ __launch_bounds__(256) void keyscatter_kernel(
    const unsigned* __restrict__ efin2, const int* __restrict__ chunk_ptr,
    const int* __restrict__ key_ptr, const int* __restrict__ blk_off_key,
    unsigned long long* __restrict__ epk3) {
    __shared__ int lcur[NKEY];
    int c = blockIdx.x, t = threadIdx.x;
    int e0 = chunk_ptr[c], n = chunk_ptr[c + 1] - e0;
    for (int k = t; k < NKEY; k += 256)
        lcur[k] = key_ptr[k] + blk_off_key[k * NCH + c];
    __syncthreads();
    for (int i = t; i < n; i += 256) {
        unsigned v = efin2[e0 + i];
        int rel = v >> 16;
        int srcv = v & 0xFFFFu;
        int k = rel * NSW + (srcv >> 13);
        int pos = atomicAdd(&lcur[k], 1);
        epk3[pos] = (unsigned long long)srcv |
                    ((unsigned long long)(unsigned)(e0 + i) << 32);
    }
}

// ================= phase 1: MFMA message kernel — zero-LDS, 4-col-interleaved B (R5-exact) =======

__device__ inline unsigned pack2bf(float x, float y) {
    unsigned short ux = __hip_bfloat16_raw(__float2bfloat16(x)).x;
    unsigned short uy = __hip_bfloat16_raw(__float2bfloat16(y)).x;
    return (unsigned)ux | ((unsigned)uy << 16);
}

__global__ __launch_bounds__(256) void msg_mfma_kernel(
    const __hip_bfloat16* __restrict__ hb, const __hip_bfloat16* __restrict__ Wt,
    const int* __restrict__ rel_ptr, const int* __restrict__ tile_base,
    const unsigned long long* __restrict__ epk3,
    __hip_bfloat16* __restrict__ msg) {
    int t = threadIdx.x;
    int w = t >> 6, lane = t & 63;
    int quad = lane >> 4, m16 = lane & 15;
    int wave = blockIdx.x * 4 + w;

    int ntiles = tile_base[N_RELS];
    int tpw = (ntiles + NWAVES - 1) / NWAVES;
    int T = wave * tpw;
    int T1 = T + tpw; if (T1 > ntiles) T1 = ntiles;
    if (T >= T1) return;

    int r = 0;
    while (T >= tile_base[r + 1]) ++r;

    while (T < T1) {
        int chunk_end = tile_base[r + 1]; if (chunk_end > T1) chunk_end = T1;
        int e_base = rel_ptr[r], t_base = tile_base[r];
        int seg_end = rel_ptr[r + 1];

        const __hip_bfloat16* Wr = Wt + (size_t)r * (DIM * DIM);
        short8 bf00 = *(const short8*)(Wr + (4 * m16)     * DIM + quad * 8);
        short8 bf01 = *(const short8*)(Wr + (4 * m16 + 1) * DIM + quad * 8);
        short8 bf02 = *(const short8*)(Wr + (4 * m16 + 2) * DIM + quad * 8);
        short8 bf03 = *(const short8*)(Wr + (4 * m16 + 3) * DIM + quad * 8);
        short8 bf10 = *(const short8*)(Wr + (4 * m16)     * DIM + 32 + quad * 8);
        short8 bf11 = *(const short8*)(Wr + (4 * m16 + 1) * DIM + 32 + quad * 8);
        short8 bf12 = *(const short8*)(Wr + (4 * m16 + 2) * DIM + 32 + quad * 8);
        short8 bf13 = *(const short8*)(Wr + (4 * m16 + 3) * DIM + 32 + quad * 8);

        // final (src, dpos) precomputed by the sort — single 8B load, no dependent lookups
        auto loadidx = [&](int TT, int& sv, int& dp) {
            int TC = TT < chunk_end ? TT : chunk_end - 1;
            int i = e_base + (TC - t_base) * 16 + lane;
            if (i >= N_EDGES) i = N_EDGES - 1;
            unsigned long long e = epk3[i];
            sv = (int)(e & 0xFFFFu);
            dp = (int)(e >> 32);
        };
        auto gatherA = [&](int sv, short8& x0, short8& x1) {
            int s = __shfl(sv, m16);
            const __hip_bfloat16* hp = hb + (size_t)s * DIM + quad * 8;
            x0 = *(const short8*)hp;
            x1 = *(const short8*)(hp + 32);
        };

        int sv0, dp0, sv1, dp1, sv2, dp2;
        short8 a0c, a1c, a0n, a1n;
        loadidx(T,     sv0, dp0);
        loadidx(T + 1, sv1, dp1);
        gatherA(sv0, a0c, a1c);

        for (; T < chunk_end; ++T) {
            loadidx(T + 2, sv2, dp2);
            gatherA(sv1, a0n, a1n);

            int e0 = e_base + (T - t_base) * 16;
            int rows = seg_end - e0; if (rows > 16) rows = 16;

            f32x4 c0 = {0.f, 0.f, 0.f, 0.f}, c1 = c0, c2 = c0, c3 = c0;
            c0 = __builtin_amdgcn_mfma_f32_16x16x32_bf16(a0c, bf00, c0, 0, 0, 0);
            c1 = __builtin_amdgcn_mfma_f32_16x16x32_bf16(a0c, bf01, c1, 0, 0, 0);
            c2 = __builtin_amdgcn_mfma_f32_16x16x32_bf16(a0c, bf02, c2, 0, 0, 0);
            c3 = __builtin_amdgcn_mfma_f32_16x16x32_bf16(a0c, bf03, c3, 0, 0, 0);
            c0 = __builtin_amdgcn_mfma_f32_16x16x32_bf16(a1c, bf10, c0, 0, 0, 0);
            c1 = __builtin_amdgcn_mfma_f32_16x16x32_bf16(a1c, bf11, c1, 0, 0, 0);
            c2 = __builtin_amdgcn_mfma_f32_16x16x32_bf16(a1c, bf12, c2, 0, 0, 0);
            c3 = __builtin_amdgcn_mfma_f32_16x16x32_bf16(a1c, bf13, c3, 0, 0, 0);

            int dpr[4];
            #pragma unroll
            for (int g = 0; g < 4; ++g) dpr[g] = __shfl(dp0, quad * 4 + g);

            #pragma unroll
            for (int g = 0; g < 4; ++g) {
                if (quad * 4 + g < rows) {
                    uint2 pk;
                    pk.x = pack2bf(c0[g], c1[g]);
                    pk.y = pack2bf(c2[g], c3[g]);
                    *(uint2*)(msg + (size_t)dpr[g] * DIM + 4 * m16) = pk;
                }
            }

            sv0 = sv1; dp0 = dp1; sv1 = sv2; dp1 = dp2;
            a0c = a0n; a1c = a1n;
        }
        ++r;
        while (T < T1 && T >= tile_base[r + 1]) ++r;
    }
}

// ================= phase 2: vectorized pull-aggregate + bias + ReLU (R5-exact) =================

__global__ __launch_bounds__(256) void agg_kernel(
    const __hip_bfloat16* __restrict__ msg, const int* __restrict__ row_ptr,
    const int* __restrict__ cnt_d, const float* __restrict__ b,
    __hip_bfloat16* __restrict__ hout) {
    int wave = blockIdx.x * 4 + (threadIdx.x >> 6);
    int lane = threadIdx.x & 63;
    if (wave >= N_NODES) return;
    int j0 = row_ptr[wave];
    int n  = cnt_d[wave];
    int rgrp = lane >> 3, dgrp = lane & 7;

    float a[8] = {0.f, 0.f, 0.f, 0.f, 0.f, 0.f, 0.f, 0.f};
    for (int jj = 0; jj < n; jj += 8) {
        int row = jj + rgrp;
        if (row < n) {
            uint4 d = *(const uint4*)(msg + (size_t)(j0 + row) * DIM + dgrp * 8);
            a[0] += __uint_as_float(d.x << 16);
            a[1] += __uint_as_float(d.x & 0xffff0000u);
            a[2] += __uint_as_float(d.y << 16);
            a[3] += __uint_as_float(d.y & 0xffff0000u);
            a[4] += __uint_as_float(d.z << 16);
            a[5] += __uint_as_float(d.z & 0xffff0000u);
            a[6] += __uint_as_float(d.w << 16);
            a[7] += __uint_as_float(d.w & 0xffff0000u);
        }
    }
    #pragma unroll
    for (int i = 0; i < 8; ++i) {
        a[i] += __shfl_xor(a[i], 8);
        a[i] += __shfl_xor(a[i], 16);
        a[i] += __shfl_xor(a[i], 32);
    }
    if (rgrp == 0) {
        unsigned short us[8];
        #pragma unroll
        for (int i = 0; i < 8; ++i) {
            float v = a[i] + b[dgrp * 8 + i];
            us[i] = __hip_bfloat16_raw(__float2bfloat16(v > 0.f ? v : 0.f)).x;
        }
        *(uint4*)(hout + (size_t)wave * DIM + dgrp * 8) = *(const uint4*)us;
    }
}

// ================= fused pool + FC x3 + prediction head =================

__global__ __launch_bounds__(256) void poolfc_kernel(
    const __hip_bfloat16* __restrict__ h, const int* __restrict__ g_ptr,
    const int* __restrict__ cnt_g,
    const float* __restrict__ W1, const float* __restrict__ b1,
    const float* __restrict__ W2, const float* __restrict__ b2,
    const float* __restrict__ W3, const float* __restrict__ b3,
    const float* __restrict__ pW, const float* __restrict__ pb,
    float* __restrict__ out) {
    int wave = blockIdx.x * 4 + (threadIdx.x >> 6);
    int lane = threadIdx.x & 63;
    if (wave >= N_GRAPHS) return;
    int j0 = g_ptr[wave];
    int n  = cnt_g[wave];
    int rgrp = lane >> 3, dgrp = lane & 7;

    float a[8] = {0.f, 0.f, 0.f, 0.f, 0.f, 0.f, 0.f, 0.f};
    for (int jj = 0; jj < n; jj += 8) {
        int row = jj + rgrp;
        if (row < n) {
            uint4 d = *(const uint4*)(h + (size_t)(j0 + row) * DIM + dgrp * 8);
            a[0] += __uint_as_float(d.x << 16);
            a[1] += __uint_as_float(d.x & 0xffff0000u);
            a[2] += __uint_as_float(d.y << 16);
            a[3] += __uint_as_float(d.y & 0xffff0000u);
            a[4] += __uint_as_float(d.z << 16);
            a[5] += __uint_as_float(d.z & 0xffff0000u);
            a[6] += __uint_as_float(d.w << 16);
            a[7] += __uint_as_float(d.w & 0xffff0000u);
        }
    }
    #pragma unroll
    for (int i = 0; i < 8; ++i) {
        a[i] += __shfl_xor(a[i], 8);
        a[i] += __shfl_xor(a[i], 16);
        a[i] += __shfl_xor(a[i], 32);
    }
    float v;
    {
        float acc = b1[lane];
        #pragma unroll
        for (int o = 0; o < 8; ++o)
            #pragma unroll
            for (int q = 0; q < 8; ++q)
                acc += __shfl(a[o], q) * W1[(q * 8 + o) * DIM + lane];
        v = acc > 0.f ? acc : 0.f;
    }
    {
        float acc = b2[lane];
        #pragma unroll
        for (int d = 0; d < DIM; ++d)
            acc += __shfl(v, d) * W2[d * DIM + lane];
        v = acc > 0.f ? acc : 0.f;
    }
    {
        float acc = b3[lane];
        #pragma unroll
        for (int d = 0; d < DIM; ++d)
            acc += __shfl(v, d) * W3[d * DIM + lane];
        v = acc > 0.f ? acc : 0.f;
    }
    float p0 = v * pW[lane * 2 + 0];
    float p1 = v * pW[lane * 2 + 1];
    #pragma unroll
    for (int off = 32; off > 0; off >>= 1) {
        p0 += __shfl_down(p0, off);
        p1 += __shfl_down(p1, off);
    }
    if (lane == 0) {
        out[wave * 2 + 0] = p0 + pb[0];
        out[wave * 2 + 1] = p1 + pb[1];
    }
}

// ================= launch =================

extern "C" void kernel_launch(void* const* d_in, const int* in_sizes, int n_in,
                              void* d_out, int out_size, void* d_ws, size_t ws_size,
                              hipStream_t stream) {
    const float* node_feats = (const float*)d_in[0];
    const int*   etypes     = (const int*)d_in[1];
    const int*   src        = (const int*)d_in[2];
    const int*   dst        = (const int*)d_in[3];
    const int*   graph_ids  = (const int*)d_in[4];
    const float* W1 = (const float*)d_in[5];
    const float* b1 = (const float*)d_in[6];
    const float* W2 = (const float*)d_in[7];
    const float* b2 = (const float*)d_in[8];
    const float* W3 = (const float*)d_in[9];
    const float* b3 = (const float*)d_in[10];
    const float* fcW1 = (const float*)d_in[11];
    const float* fcb1 = (const float*)d_in[12];
    const float* fcW2 = (const float*)d_in[13];
    const float* fcb2 = (const float*)d_in[14];
    const float* fcW3 = (const float*)d_in[15];
    const float* fcb3 = (const float*)d_in[16];
    const float* pW = (const float*)d_in[17];
    const float* pb = (const float*)d_in[18];
    float* out = (float*)d_out;

    // workspace carve-up (256B aligned)
    char* p = (char*)d_ws;
    auto alloc = [&](size_t bytes) -> void* {
        void* r = (void*)p;
        p += (bytes + 255) & ~(size_t)255;
        return r;
    };
    int* blk_hist3  = (int*)alloc((size_t)NCH * SB3 * sizeof(int));
    int* blk_off3   = (int*)alloc((size_t)NCH * SB3 * sizeof(int));
    int* chunk_tot  = (int*)alloc(NCH * sizeof(int));
    int* chunk_ptr  = (int*)alloc((NCH + 1) * sizeof(int));
    unsigned* epk2  = (unsigned*)alloc((size_t)N_EDGES * sizeof(unsigned));
    unsigned* efin2 = (unsigned*)alloc((size_t)N_EDGES * sizeof(unsigned));
    unsigned long long* epk3 = (unsigned long long*)alloc((size_t)N_EDGES * sizeof(unsigned long long));
    int* keyh_g     = (int*)alloc((size_t)NKEY * NCH * sizeof(int));
    int* blk_off_key= (int*)alloc((size_t)NKEY * NCH * sizeof(int));
    int* key_tot    = (int*)alloc(NKEY * sizeof(int));
    int* key_ptr    = (int*)alloc((NKEY + 1) * sizeof(int));
    int* rel_ptr    = (int*)alloc((N_RELS + 1) * sizeof(int));
    int* tile_base  = (int*)alloc((N_RELS + 1) * sizeof(int));
    int* cnt_d      = (int*)alloc((size_t)N_NODES * sizeof(int));
    int* row_ptr    = (int*)alloc((size_t)N_NODES * sizeof(int));
    int* cnt_g      = (int*)alloc(N_GRAPHS * sizeof(int));
    int* g_ptr      = (int*)alloc(N_GRAPHS * sizeof(int));
    int* done_flags = (int*)alloc(2 * sizeof(int));
    __hip_bfloat16* hb0 = (__hip_bfloat16*)alloc((size_t)N_NODES * DIM * sizeof(__hip_bfloat16));
    __hip_bfloat16* hb1 = (__hip_bfloat16*)alloc((size_t)N_NODES * DIM * sizeof(__hip_bfloat16));
    __hip_bfloat16* Wt1 = (__hip_bfloat16*)alloc((size_t)N_RELS * DIM * DIM * sizeof(__hip_bfloat16));
    __hip_bfloat16* Wt2 = (__hip_bfloat16*)alloc((size_t)N_RELS * DIM * DIM * sizeof(__hip_bfloat16));
    __hip_bfloat16* Wt3 = (__hip_bfloat16*)alloc((size_t)N_RELS * DIM * DIM * sizeof(__hip_bfloat16));
    __hip_bfloat16* msg = (__hip_bfloat16*)alloc((size_t)N_EDGES * DIM * sizeof(__hip_bfloat16));

    const int AGG_BLOCKS = (N_NODES + 3) / 4;            // 12500

    // ---- prep: atomic-free two-level sort, (rel,srcwin)-keyed (6 dispatches) ----
    prep_kernel<<<1024, 256, 0, stream>>>(node_feats, dst, hb0, blk_hist3,
                                          W1, W2, W3, Wt1, Wt2, Wt3, done_flags);
    chunkscan_kernel<<<NCH, 256, 0, stream>>>(blk_hist3, blk_off3, chunk_tot, chunk_ptr,
                                              graph_ids, g_ptr, cnt_g, &done_flags[0]);
    scatterc_kernel<<<SB3, 256, 0, stream>>>(etypes, src, dst, blk_hist3, blk_off3,
                                             chunk_ptr, epk2);
    chunksort_kernel<<<NCH, 256, 0, stream>>>(epk2, chunk_ptr, efin2, cnt_d,
                                              row_ptr, keyh_g);
    keyscan_kernel<<<NKEY, 128, 0, stream>>>(keyh_g, blk_off_key, key_tot, key_ptr,
                                             rel_ptr, tile_base, &done_flags[1]);
    keyscatter_kernel<<<NCH, 256, 0, stream>>>(efin2, chunk_ptr, key_ptr,
                                               blk_off_key, epk3);

    // ---- 3 RGCN layers ----
    msg_mfma_kernel<<<MSG_BLOCKS, 256, 0, stream>>>(hb0, Wt1, rel_ptr, tile_base,
                                                    epk3, msg);
    agg_kernel<<<AGG_BLOCKS, 256, 0, stream>>>(msg, row_ptr, cnt_d, b1, hb1);

    msg_mfma_kernel<<<MSG_BLOCKS, 256, 0, stream>>>(hb1, Wt2, rel_ptr, tile_base,
                                                    epk3, msg);
    agg_kernel<<<AGG_BLOCKS, 256, 0, stream>>>(msg, row_ptr, cnt_d, b2, hb0);

    msg_mfma_kernel<<<MSG_BLOCKS, 256, 0, stream>>>(hb0, Wt3, rel_ptr, tile_base,
                                                    epk3, msg);
    agg_kernel<<<AGG_BLOCKS, 256, 0, stream>>>(msg, row_ptr, cnt_d, b3, hb1);

    // ---- fused pool + FC head ----
    poolfc_kernel<<<(N_GRAPHS + 3) / 4, 256, 0, stream>>>(hb1, g_ptr, cnt_g,
                                                          fcW1, fcb1, fcW2, fcb2,
                                                          fcW3, fcb3, pW, pb, out);
}